// Round 5
// baseline (294.553 us; speedup 1.0000x reference)
//
#include <hip/hip_runtime.h>
#include <hip/hip_bf16.h>
#include <math.h>

// Problem constants
#define B_   2
#define T_   2048
#define D_   2048
#define NH_  16
#define NKV_ 4
#define HD_  128
#define MROWS (B_*T_)          // 4096
#define NQKV  (NH_*HD_ + 2*NKV_*HD_)  // 3072

typedef __bf16 bf16_t;
typedef __bf16 bf16x8 __attribute__((ext_vector_type(8)));
typedef __bf16 bf16x4 __attribute__((ext_vector_type(4)));
typedef float  floatx4 __attribute__((ext_vector_type(4)));

// ---------------------------------------------------------------------------
// async global->LDS, 16B per lane. LDS dest must be wave-uniform base + lane*16.
__device__ __forceinline__ void async_copy16(const bf16_t* gsrc, bf16_t* ldst) {
  __builtin_amdgcn_global_load_lds(
      (const __attribute__((address_space(1))) unsigned int*)gsrc,
      (__attribute__((address_space(3))) unsigned int*)ldst, 16, 0, 0);
}

// ---------------------------------------------------------------------------
// cast fp32 -> bf16, 8 elems/thread
__global__ void cast_f32_bf16(const float* __restrict__ src, bf16_t* __restrict__ dst, int n) {
  int i = (blockIdx.x * 256 + threadIdx.x) * 8;
  if (i >= n) return;
  float4 a = *(const float4*)(src + i);
  float4 b = *(const float4*)(src + i + 4);
  bf16x8 v;
  v[0]=(bf16_t)a.x; v[1]=(bf16_t)a.y; v[2]=(bf16_t)a.z; v[3]=(bf16_t)a.w;
  v[4]=(bf16_t)b.x; v[5]=(bf16_t)b.y; v[6]=(bf16_t)b.z; v[7]=(bf16_t)b.w;
  *(bf16x8*)(dst + i) = v;
}

// ---------------------------------------------------------------------------
// transpose + cast: src (K,N) fp32 row-major -> dst (N,K) bf16 row-major
// grid (N/32, K/32), block (32,8)
__global__ void transpose_cast(const float* __restrict__ src, bf16_t* __restrict__ dst,
                               int K, int N) {
  __shared__ float tile[32][33];
  int n0 = blockIdx.x * 32, k0 = blockIdx.y * 32;
  int tx = threadIdx.x, ty = threadIdx.y;
#pragma unroll
  for (int r = 0; r < 4; r++)
    tile[ty + r*8][tx] = src[(size_t)(k0 + ty + r*8) * N + n0 + tx];
  __syncthreads();
#pragma unroll
  for (int r = 0; r < 4; r++)
    dst[(size_t)(n0 + ty + r*8) * K + k0 + tx] = (bf16_t)tile[tx][ty + r*8];
}

// ---------------------------------------------------------------------------
// C(M,N) = A(M,K) * Bt(N,K)^T   all bf16 in, OUT_T out.
// 128x128 tile, BK=64, 4 waves (2x2 of 64x64), 16x16x32 MFMA.
template <typename OUT_T>
__global__ __launch_bounds__(256, 2)
void gemm_bt(const bf16_t* __restrict__ A, const bf16_t* __restrict__ Bt,
             OUT_T* __restrict__ C, int M, int N, int K) {
  __shared__ __align__(16) bf16_t As[128 * 64];
  __shared__ __align__(16) bf16_t Bs[128 * 64];
  const int tid  = threadIdx.x;
  const int wave = tid >> 6, lane = tid & 63;
  const int quad = lane >> 4, l16 = lane & 15;
  const int nBlocksM = M >> 7;
  const int bm = blockIdx.x % nBlocksM, bn = blockIdx.x / nBlocksM;
  const int m0 = bm * 128, n0 = bn * 128;
  const int wm = (wave >> 1) * 64, wn = (wave & 1) * 64;

  floatx4 acc[4][4];
#pragma unroll
  for (int i = 0; i < 4; i++)
#pragma unroll
    for (int j = 0; j < 4; j++) acc[i][j] = floatx4{0.f, 0.f, 0.f, 0.f};

  for (int k0 = 0; k0 < K; k0 += 64) {
    __syncthreads();
#pragma unroll
    for (int i = 0; i < 4; i++) {
      int e = i * 256 + tid;
      int row = e >> 3, grp = e & 7;
      int gg = grp ^ (row & 7);
      async_copy16(A + (size_t)(m0 + row) * K + k0 + gg * 8, As + e * 8);
    }
#pragma unroll
    for (int i = 0; i < 4; i++) {
      int e = i * 256 + tid;
      int row = e >> 3, grp = e & 7;
      int gg = grp ^ (row & 7);
      async_copy16(Bt + (size_t)(n0 + row) * K + k0 + gg * 8, Bs + e * 8);
    }
    __syncthreads();
#pragma unroll
    for (int ks = 0; ks < 2; ks++) {
      bf16x8 af[4], bfr[4];
      int grp = ks * 4 + quad;
#pragma unroll
      for (int mi = 0; mi < 4; mi++) {
        int row = wm + mi * 16 + l16;
        af[mi] = *(const bf16x8*)(As + row * 64 + ((grp ^ (row & 7)) << 3));
      }
#pragma unroll
      for (int ni = 0; ni < 4; ni++) {
        int row = wn + ni * 16 + l16;
        bfr[ni] = *(const bf16x8*)(Bs + row * 64 + ((grp ^ (row & 7)) << 3));
      }
#pragma unroll
      for (int mi = 0; mi < 4; mi++)
#pragma unroll
        for (int ni = 0; ni < 4; ni++)
          acc[mi][ni] = __builtin_amdgcn_mfma_f32_16x16x32_bf16(af[mi], bfr[ni], acc[mi][ni], 0, 0, 0);
    }
  }
  // epilogue: C row = quad*4+reg (+16*mi), col = lane&15 (+16*ni)  [m89/m91 layout]
#pragma unroll
  for (int mi = 0; mi < 4; mi++) {
#pragma unroll
    for (int r = 0; r < 4; r++) {
      int row = m0 + wm + mi * 16 + quad * 4 + r;
      size_t base = (size_t)row * N + n0 + wn;
#pragma unroll
      for (int ni = 0; ni < 4; ni++)
        C[base + ni * 16 + l16] = (OUT_T)acc[mi][ni][r];
    }
  }
}

// ---------------------------------------------------------------------------
// RoPE + scatter: qkv (4096, 3072) bf16 -> Qb (B,NH,T,HD) scaled+roped,
//                 Kb (B,NKV,T,HD) roped.  One thread per (row, head, j<64).
// Q scale = 1/sqrt(128) * log2(e)  (flash softmax runs in exp2 domain)
__global__ void rope_scatter(const bf16_t* __restrict__ qkv,
                             bf16_t* __restrict__ Qb, bf16_t* __restrict__ Kb) {
  int g = blockIdx.x * 256 + threadIdx.x;
  int j = g & 63;
  int rest = g >> 6;
  int head = rest % (NH_ + NKV_);
  int row  = rest / (NH_ + NKV_);     // b*T + t
  int t = row & (T_ - 1);
  int b = row >> 11;                  // T_ = 2048
  const bf16_t* src = qkv + (size_t)row * NQKV;
  // inv_freq = 10000^(-j/64) = exp(-j * ln(10000)/64)
  float ang = (float)t * expf(-0.14391156816f * (float)j);
  float sn, cs;
  sincosf(ang, &sn, &cs);
  if (head < NH_) {
    float x0 = (float)src[head * HD_ + j];
    float x1 = (float)src[head * HD_ + 64 + j];
    const float scale = 0.12751651541057752f;  // 1/sqrt(128)*log2(e)
    bf16_t* dst = Qb + ((size_t)(b * NH_ + head) * T_ + t) * HD_;
    dst[j]      = (bf16_t)((x0 * cs - x1 * sn) * scale);
    dst[j + 64] = (bf16_t)((x1 * cs + x0 * sn) * scale);
  } else {
    int kvh = head - NH_;
    float x0 = (float)src[NH_ * HD_ + kvh * HD_ + j];
    float x1 = (float)src[NH_ * HD_ + kvh * HD_ + 64 + j];
    bf16_t* dst = Kb + ((size_t)(b * NKV_ + kvh) * T_ + t) * HD_;
    dst[j]      = (bf16_t)(x0 * cs - x1 * sn);
    dst[j + 64] = (bf16_t)(x1 * cs + x0 * sn);
  }
}

// ---------------------------------------------------------------------------
// V transpose: qkv V-slice (b,t,kv,d) -> Vt (B,NKV,HD,T)
__global__ void v_transpose(const bf16_t* __restrict__ qkv, bf16_t* __restrict__ Vt) {
  __shared__ float tile[32][33];
  int t0 = blockIdx.x * 32, d0 = blockIdx.y * 32;
  int bk = blockIdx.z;
  int b = bk / NKV_, kvh = bk % NKV_;
  int tx = threadIdx.x, ty = threadIdx.y;
#pragma unroll
  for (int r = 0; r < 4; r++) {
    int t = t0 + ty + r * 8;
    tile[ty + r*8][tx] =
        (float)qkv[(size_t)(b * T_ + t) * NQKV + (NH_ + NKV_) * HD_ + kvh * HD_ + d0 + tx];
  }
  __syncthreads();
#pragma unroll
  for (int r = 0; r < 4; r++) {
    int d = d0 + ty + r * 8;
    Vt[((size_t)(b * NKV_ + kvh) * HD_ + d) * T_ + t0 + tx] = (bf16_t)tile[tx][ty + r*8];
  }
}

// ---------------------------------------------------------------------------
// Flash attention v5: S^T formulation + TWO HEADS PER BLOCK.
// Heads in the same GQA group share K/V, so one K/V staging (and one set of
// kf/vf LDS reads) feeds 64 MFMAs/iter instead of 32. Ps is reused
// sequentially per head (wave-private, in-order DS) -> LDS unchanged.
// Staging pointers hoisted out of the kt-loop (+= stride, no recompute).
// Alpha-rescale skipped wave-uniformly when no lane's running max changed.
__global__ __launch_bounds__(256, 2)
void flash_attn(const bf16_t* __restrict__ Qb, const bf16_t* __restrict__ Kb,
                const bf16_t* __restrict__ Vt, bf16_t* __restrict__ Ob) {
  __shared__ __align__(16) bf16_t Ks[2][64 * 128];   // (key, d), swizzle grp^(row&15)
  __shared__ __align__(16) bf16_t Vs[2][128 * 64];   // (d, key), swizzle grp^(row&7)
  __shared__ __align__(16) bf16_t Ps[4][16 * 72];    // wave-private P^T: [q][key], +8 pad

  const int tid = threadIdx.x;
  const int wave = tid >> 6, lane = tid & 63;
  const int quad = lane >> 4, l16 = lane & 15;
  const int nQT = T_ / 64;             // 32
  const int NPAIR = B_ * NKV_ * 2;     // 16 head-pairs
  const int bid = blockIdx.x;
  const int pair = bid % NPAIR;
  const int qt = (nQT - 1) - (bid / NPAIR);   // heavy-first
  const int hp = pair & 1;
  const int bkv = pair >> 1;
  const int kv = bkv % NKV_;
  const int b = bkv / NKV_;
  const int h0 = kv * 4 + hp * 2;      // this block: heads h0, h0+1 (same kv)

  const bf16_t* kbase = Kb + ((size_t)(b * NKV_ + kv) * T_) * HD_;
  const bf16_t* vbase = Vt + ((size_t)(b * NKV_ + kv) * HD_) * T_;

  // hoisted staging source pointers (advance by stride per kt)
  const bf16_t* kptr[4];
  const bf16_t* vptr[4];
#pragma unroll
  for (int i = 0; i < 4; i++) {
    int e = i * 256 + tid;
    { int row = e >> 4, grp = e & 15; int gg = grp ^ (row & 15);
      kptr[i] = kbase + (size_t)row * HD_ + gg * 8; }
    { int row = e >> 3, grp = e & 7;  int gg = grp ^ (row & 7);
      vptr[i] = vbase + (size_t)row * T_ + gg * 8; }
  }

  auto stage = [&](int bufi) {
#pragma unroll
    for (int i = 0; i < 4; i++) {
      async_copy16(kptr[i], &Ks[bufi][(i * 256 + tid) * 8]);
      kptr[i] += 64 * HD_;
    }
#pragma unroll
    for (int i = 0; i < 4; i++) {
      async_copy16(vptr[i], &Vs[bufi][(i * 256 + tid) * 8]);
      vptr[i] += 64;
    }
  };

  stage(0);  // prefetch first tile

  // Q fragments (B-operand): lane n=l16 -> q row, holds d = ks*32+quad*8+j
  bf16x8 qf[2][4];
#pragma unroll
  for (int hd = 0; hd < 2; hd++) {
    const bf16_t* qptr =
        Qb + ((size_t)(b * NH_ + h0 + hd) * T_ + qt * 64 + wave * 16 + l16) * HD_;
#pragma unroll
    for (int ks = 0; ks < 4; ks++)
      qf[hd][ks] = *(const bf16x8*)(qptr + ks * 32 + quad * 8);
  }

  // O^T accumulators per head: o[hd][dt][r] = O^T[d = dt*16+quad*4+r][q = l16]
  floatx4 o[2][8];
#pragma unroll
  for (int hd = 0; hd < 2; hd++)
#pragma unroll
    for (int i = 0; i < 8; i++) o[hd][i] = floatx4{0.f, 0.f, 0.f, 0.f};
  float m_s[2] = {-1e30f, -1e30f};
  float l_s[2] = {0.f, 0.f};

  for (int kt = 0; kt <= qt; kt++) {
    const int bufi = kt & 1;
    // barrier: drains vmcnt (staging of THIS tile, issued last iter, is done)
    // and protects the buffer we are about to overwrite.
    __syncthreads();
    if (kt < qt) stage(bufi ^ 1);  // prefetch next tile (other buffer)

    // S^T = K Q^T for both heads; kf loaded ONCE, used twice
    floatx4 s[2][4];
#pragma unroll
    for (int hd = 0; hd < 2; hd++)
#pragma unroll
      for (int nt = 0; nt < 4; nt++) s[hd][nt] = floatx4{0.f, 0.f, 0.f, 0.f};
#pragma unroll
    for (int ks = 0; ks < 4; ks++) {
      int grp = ks * 4 + quad;
#pragma unroll
      for (int nt = 0; nt < 4; nt++) {
        int row = nt * 16 + l16;
        bf16x8 kf = *(const bf16x8*)(&Ks[bufi][row * 128 + ((grp ^ (row & 15)) << 3)]);
        s[0][nt] = __builtin_amdgcn_mfma_f32_16x16x32_bf16(kf, qf[0][ks], s[0][nt], 0, 0, 0);
        s[1][nt] = __builtin_amdgcn_mfma_f32_16x16x32_bf16(kf, qf[1][ks], s[1][nt], 0, 0, 0);
      }
    }

    // causal mask (diagonal tile only): key_local > q_local
    if (kt == qt) {
      int qlocal = wave * 16 + l16;
#pragma unroll
      for (int nt = 0; nt < 4; nt++)
#pragma unroll
        for (int r = 0; r < 4; r++) {
          int klocal = nt * 16 + quad * 4 + r;
          if (klocal > qlocal) { s[0][nt][r] = -1e30f; s[1][nt][r] = -1e30f; }
        }
    }

    // per-head: online softmax (exp2 domain) + P^T/PV through shared Ps
#pragma unroll
    for (int hd = 0; hd < 2; hd++) {
      float mx = fmaxf(fmaxf(s[hd][0][0], s[hd][0][1]), fmaxf(s[hd][0][2], s[hd][0][3]));
#pragma unroll
      for (int nt = 1; nt < 4; nt++)
        mx = fmaxf(mx, fmaxf(fmaxf(s[hd][nt][0], s[hd][nt][1]),
                             fmaxf(s[hd][nt][2], s[hd][nt][3])));
      mx = fmaxf(mx, __shfl_xor(mx, 16, 64));
      mx = fmaxf(mx, __shfl_xor(mx, 32, 64));
      float mold = m_s[hd];
      float mnew = fmaxf(mold, mx);
      m_s[hd] = mnew;
      float sum = 0.f;
#pragma unroll
      for (int nt = 0; nt < 4; nt++)
#pragma unroll
        for (int r = 0; r < 4; r++) {
          float p = __builtin_amdgcn_exp2f(s[hd][nt][r] - mnew);
          s[hd][nt][r] = p;
          sum += p;
        }
      sum += __shfl_xor(sum, 16, 64);
      sum += __shfl_xor(sum, 32, 64);
      // wave-uniform skip: running max usually doesn't move once kt is large
      if (__any(mnew > mold)) {
        float alpha = __builtin_amdgcn_exp2f(mold - mnew);
        l_s[hd] = l_s[hd] * alpha + sum;
#pragma unroll
        for (int dt = 0; dt < 8; dt++) o[hd][dt] *= alpha;
      } else {
        l_s[hd] += sum;
      }

      // P^T -> LDS: row q=l16, keys nt*16+quad*4..+3 as one 8B write
#pragma unroll
      for (int nt = 0; nt < 4; nt++) {
        bf16x4 p4;
#pragma unroll
        for (int r = 0; r < 4; r++) p4[r] = (bf16_t)s[hd][nt][r];
        *(bf16x4*)(&Ps[wave][l16 * 72 + nt * 16 + quad * 4]) = p4;
      }

      // O^T += V^T P^T (wave-private Ps: in-order DS, no barrier needed)
#pragma unroll
      for (int ks = 0; ks < 2; ks++) {
        bf16x8 pf = *(const bf16x8*)(&Ps[wave][l16 * 72 + ks * 32 + quad * 8]);
        int grp = ks * 4 + quad;
#pragma unroll
        for (int dt = 0; dt < 8; dt++) {
          int row = dt * 16 + l16;
          bf16x8 vf = *(const bf16x8*)(&Vs[bufi][row * 64 + ((grp ^ (row & 7)) << 3)]);
          o[hd][dt] = __builtin_amdgcn_mfma_f32_16x16x32_bf16(vf, pf, o[hd][dt], 0, 0, 0);
        }
      }
    }
  }

  // epilogue: lane owns q-row qg; d = dt*16+quad*4+r, packed 8B stores
#pragma unroll
  for (int hd = 0; hd < 2; hd++) {
    int qg = qt * 64 + wave * 16 + l16;
    float inv_l = 1.f / l_s[hd];
    size_t base = ((size_t)(b * T_) + qg) * D_ + (h0 + hd) * HD_;
#pragma unroll
    for (int dt = 0; dt < 8; dt++) {
      bf16x4 w;
#pragma unroll
      for (int r = 0; r < 4; r++) w[r] = (bf16_t)(o[hd][dt][r] * inv_l);
      *(bf16x4*)(Ob + base + dt * 16 + quad * 4) = w;
    }
  }
}

// ---------------------------------------------------------------------------
extern "C" void kernel_launch(void* const* d_in, const int* in_sizes, int n_in,
                              void* d_out, int out_size, void* d_ws, size_t ws_size,
                              hipStream_t stream) {
  const float* x  = (const float*)d_in[0];
  const float* wq = (const float*)d_in[1];
  const float* wk = (const float*)d_in[2];
  const float* wv = (const float*)d_in[3];
  const float* wo = (const float*)d_in[4];
  float* out = (float*)d_out;

  // workspace layout (bf16 elems); attn output aliases x_bf (x_bf dead after GEMM1)
  bf16_t* x_bf   = (bf16_t*)d_ws;                          // 4096*2048
  bf16_t* attn_o = x_bf;                                   // alias
  bf16_t* wqkv_t = x_bf + (size_t)MROWS * D_;              // 3072*2048
  bf16_t* wo_t   = wqkv_t + (size_t)NQKV * D_;             // 2048*2048
  bf16_t* qkv    = wo_t + (size_t)D_ * D_;                 // 4096*3072
  bf16_t* Qb     = qkv + (size_t)MROWS * NQKV;             // 2*16*2048*128
  bf16_t* Kb     = Qb + (size_t)B_ * NH_ * T_ * HD_;       // 2*4*2048*128
  bf16_t* Vt     = Kb + (size_t)B_ * NKV_ * T_ * HD_;      // 2*4*128*2048

  // 1. casts / weight transposes
  cast_f32_bf16<<<(MROWS * D_) / (256 * 8), 256, 0, stream>>>(x, x_bf, MROWS * D_);
  transpose_cast<<<dim3(64, 64), dim3(32, 8), 0, stream>>>(wq, wqkv_t, D_, 2048);
  transpose_cast<<<dim3(16, 64), dim3(32, 8), 0, stream>>>(wk, wqkv_t + (size_t)2048 * D_, D_, 512);
  transpose_cast<<<dim3(16, 64), dim3(32, 8), 0, stream>>>(wv, wqkv_t + (size_t)2560 * D_, D_, 512);
  transpose_cast<<<dim3(64, 64), dim3(32, 8), 0, stream>>>(wo, wo_t, D_, 2048);

  // 2. fused QKV projection: (4096,2048) x (2048,3072) -> bf16
  gemm_bt<bf16_t><<<(MROWS / 128) * (NQKV / 128), 256, 0, stream>>>(
      x_bf, wqkv_t, qkv, MROWS, NQKV, D_);

  // 3. RoPE + GQA scatter + V transpose
  rope_scatter<<<(MROWS * (NH_ + NKV_) * 64) / 256, 256, 0, stream>>>(qkv, Qb, Kb);
  v_transpose<<<dim3(T_ / 32, HD_ / 32, B_ * NKV_), dim3(32, 8), 0, stream>>>(qkv, Vt);

  // 4. causal flash attention: 2 heads/block, double-buffered, heavy-first
  flash_attn<<<B_ * NKV_ * 2 * (T_ / 64), 256, 0, stream>>>(Qb, Kb, Vt, attn_o);

  // 5. output projection: (4096,2048) x (2048,2048) -> fp32
  gemm_bt<float><<<(MROWS / 128) * (D_ / 128), 256, 0, stream>>>(
      attn_o, wo_t, out, MROWS, D_, D_);
}